// Round 3
// baseline (373.193 us; speedup 1.0000x reference)
//
#include <hip/hip_runtime.h>
#include <hip/hip_bf16.h>

typedef short short8 __attribute__((ext_vector_type(8)));
typedef float f32x4 __attribute__((ext_vector_type(4)));
typedef int i32x4 __attribute__((ext_vector_type(4)));

#define HDIM 1024
#define TSEQ 2048
#define BATCH 4
#define NH 16
#define HD 64
#define SCALE_Q 0.18033688011f   // 0.125 * log2(e)

__device__ __forceinline__ unsigned short f2bf(float f) {
  union { float f; unsigned u; } x; x.f = f;
  unsigned r = x.u + 0x7fffu + ((x.u >> 16) & 1u);
  return (unsigned short)(r >> 16);
}

__device__ __forceinline__ unsigned pk2(float a, float b) {
  __hip_bfloat162 h2 = __float22bfloat162_rn(float2{a, b});
  union { __hip_bfloat162 h; unsigned u; } u2; u2.h = h2;
  return u2.u;
}

// 16B-slot XOR swizzle within a 128B row (8 slots)
__device__ __forceinline__ int swz(int row, int slot) { return slot ^ (row & 7); }

// ---------------- weight fp32 -> bf16 ----------------
__global__ __launch_bounds__(256) void convert_w(
    const float* __restrict__ wq, const float* __restrict__ wk,
    const float* __restrict__ wv, const float* __restrict__ wo,
    unsigned short* __restrict__ out) {
  size_t i = ((size_t)blockIdx.x * 256 + threadIdx.x) * 4;   // 4 elems/thread
  int which = (int)(i >> 20);                                // H*H = 2^20
  const float* src = which == 0 ? wq : which == 1 ? wk : which == 2 ? wv : wo;
  size_t off = i & ((1u << 20) - 1);
  float4 v = *reinterpret_cast<const float4*>(src + off);
  unsigned lo = (unsigned)f2bf(v.x) | ((unsigned)f2bf(v.y) << 16);
  unsigned hi = (unsigned)f2bf(v.z) | ((unsigned)f2bf(v.w) << 16);
  uint2 o; o.x = lo; o.y = hi;
  *reinterpret_cast<uint2*>(out + i) = o;
}

// ---------------- LayerNorm -> bf16 ----------------
__global__ __launch_bounds__(256) void ln_kernel(
    const float* __restrict__ x, const float* __restrict__ g,
    const float* __restrict__ bta, unsigned short* __restrict__ h) {
  int row = blockIdx.x;
  int tid = threadIdx.x;
  const float* xr = x + (size_t)row * HDIM;
  float4 v = *reinterpret_cast<const float4*>(xr + tid * 4);
  float s = v.x + v.y + v.z + v.w;
  float sq = v.x * v.x + v.y * v.y + v.z * v.z + v.w * v.w;
  for (int m = 32; m; m >>= 1) { s += __shfl_xor(s, m); sq += __shfl_xor(sq, m); }
  __shared__ float red[8];
  int w = tid >> 6, l = tid & 63;
  if (l == 0) { red[w] = s; red[4 + w] = sq; }
  __syncthreads();
  s = red[0] + red[1] + red[2] + red[3];
  sq = red[4] + red[5] + red[6] + red[7];
  float mu = s * (1.0f / HDIM);
  float var = sq * (1.0f / HDIM) - mu * mu;
  float inv = rsqrtf(var + 1e-5f);
  float4 gv = *reinterpret_cast<const float4*>(g + tid * 4);
  float4 bv = *reinterpret_cast<const float4*>(bta + tid * 4);
  unsigned short o0 = f2bf((v.x - mu) * inv * gv.x + bv.x);
  unsigned short o1 = f2bf((v.y - mu) * inv * gv.y + bv.y);
  unsigned short o2 = f2bf((v.z - mu) * inv * gv.z + bv.z);
  unsigned short o3 = f2bf((v.w - mu) * inv * gv.w + bv.w);
  uint2 o; o.x = (unsigned)o0 | ((unsigned)o1 << 16); o.y = (unsigned)o2 | ((unsigned)o3 << 16);
  *reinterpret_cast<uint2*>(h + (size_t)row * HDIM + tid * 4) = o;
}

// ---------------- GEMM: C = A(bf16 MxK) * W^T(bf16 NxK) + bias ----------------
// MODE 0: QKV. z=0: Q*(0.125*log2e) -> (B,NH,T,HD); z=1: K -> (B,NH,T,HD);
//         z=2: V^T -> (B,NH,HD,T)
// MODE 1: out-proj -> fp32 out = acc + bias + xres
template <int MODE>
__global__ __launch_bounds__(256) void gemm_k(
    const unsigned short* __restrict__ A, const unsigned short* __restrict__ Wb,
    const float* __restrict__ b0, const float* __restrict__ b1, const float* __restrict__ b2,
    unsigned short* __restrict__ o0, unsigned short* __restrict__ o1, unsigned short* __restrict__ o2,
    const float* __restrict__ xres, float* __restrict__ outf) {
  __shared__ __align__(16) unsigned short Alds[128 * 64];
  __shared__ __align__(16) unsigned short Wlds[128 * 64];
  const int z = blockIdx.z;
  const unsigned short* Wp = Wb + (size_t)z * HDIM * HDIM;
  const float* bias = (z == 0) ? b0 : (z == 1) ? b1 : b2;
  unsigned short* obf = (z == 0) ? o0 : (z == 1) ? o1 : o2;
  const int tid = threadIdx.x;
  const int l = tid & 63, w = tid >> 6;
  const int wr = (w >> 1) * 64, wc = (w & 1) * 64;
  const int bn = blockIdx.x, bm = blockIdx.y;
  const int lrow = l & 15, lk = l >> 4;
  f32x4 acc[4][4] = {};
  for (int kt = 0; kt < 16; ++kt) {
    __syncthreads();
#pragma unroll
    for (int p = 0; p < 4; ++p) {
      int flat = p * 256 + tid;           // 1024 chunks of 16B
      int row = flat >> 3, slot = flat & 7;
      uint4 av = *reinterpret_cast<const uint4*>(A + (size_t)(bm * 128 + row) * HDIM + kt * 64 + slot * 8);
      *reinterpret_cast<uint4*>(reinterpret_cast<char*>(Alds) + row * 128 + swz(row, slot) * 16) = av;
      uint4 wv = *reinterpret_cast<const uint4*>(Wp + (size_t)(bn * 128 + row) * HDIM + kt * 64 + slot * 8);
      *reinterpret_cast<uint4*>(reinterpret_cast<char*>(Wlds) + row * 128 + swz(row, slot) * 16) = wv;
    }
    __syncthreads();
#pragma unroll
    for (int ks = 0; ks < 2; ++ks) {
      short8 af[4], bfr[4];
#pragma unroll
      for (int rt = 0; rt < 4; ++rt) {
        int row = wr + rt * 16 + lrow;
        af[rt] = *reinterpret_cast<const short8*>(reinterpret_cast<char*>(Alds) + row * 128 + swz(row, ks * 4 + lk) * 16);
      }
#pragma unroll
      for (int ct = 0; ct < 4; ++ct) {
        int row = wc + ct * 16 + lrow;
        bfr[ct] = *reinterpret_cast<const short8*>(reinterpret_cast<char*>(Wlds) + row * 128 + swz(row, ks * 4 + lk) * 16);
      }
#pragma unroll
      for (int rt = 0; rt < 4; ++rt)
#pragma unroll
        for (int ct = 0; ct < 4; ++ct)
          acc[rt][ct] = __builtin_amdgcn_mfma_f32_16x16x32_bf16(af[rt], bfr[ct], acc[rt][ct], 0, 0, 0);
    }
  }
#pragma unroll
  for (int rt = 0; rt < 4; ++rt) {
#pragma unroll
    for (int ct = 0; ct < 4; ++ct) {
      int ncol = bn * 128 + wc + ct * 16 + lrow;
      float bv = bias[ncol];
      if (MODE == 0 && z == 2) {
        // V^T: (B,NH,HD,T); 4 consecutive t -> one 8B packed store
        int mrow0 = bm * 128 + wr + rt * 16 + lk * 4;
        int bb = mrow0 >> 11, t0 = mrow0 & (TSEQ - 1);
        int head = ncol >> 6, d = ncol & 63;
        uint2 pw;
        pw.x = pk2(acc[rt][ct][0] + bv, acc[rt][ct][1] + bv);
        pw.y = pk2(acc[rt][ct][2] + bv, acc[rt][ct][3] + bv);
        *reinterpret_cast<uint2*>(obf + ((size_t)(bb * NH + head) * HD + d) * TSEQ + t0) = pw;
      } else {
#pragma unroll
        for (int r = 0; r < 4; ++r) {
          int mrow = bm * 128 + wr + rt * 16 + lk * 4 + r;
          float val = acc[rt][ct][r] + bv;
          if (MODE == 0) {
            if (z == 0) val *= SCALE_Q;       // fold 1/sqrt(HEAD) * log2(e) into Q
            int bb = mrow >> 11, t = mrow & (TSEQ - 1);
            int head = ncol >> 6, d = ncol & 63;
            obf[((size_t)(bb * NH + head) * TSEQ + t) * HD + d] = f2bf(val);
          } else {
            size_t idx = (size_t)mrow * HDIM + ncol;
            outf[idx] = val + xres[idx];
          }
        }
      }
    }
  }
}

// ---------------- flash attention, swapped-QK^T, no staging / no barriers ----
// grid: (T/128, NH, B), block 256 (4 independent waves, each 32 q rows), KVBLK=64
// K and V^T fragments come straight from global (L1/L2-resident per head).
__global__ __launch_bounds__(256) void attn_kernel(
    const unsigned short* __restrict__ q_s, const unsigned short* __restrict__ k_s,
    const unsigned short* __restrict__ vt_s, const int* __restrict__ mask,
    unsigned short* __restrict__ c) {
  __shared__ __align__(16) unsigned short Plds[4][2048];  // 4KB per wave
  __shared__ float slds[4][32];
  const int b = blockIdx.z, head = blockIdx.y, qb = blockIdx.x;
  const unsigned short* qp = q_s + ((size_t)(b * NH + head) * TSEQ + qb * 128) * HD;
  const unsigned short* kp = k_s + (size_t)(b * NH + head) * TSEQ * HD;
  const unsigned short* vtp = vt_s + (size_t)(b * NH + head) * HD * TSEQ;
  const int* mp = mask + b * TSEQ;
  const int tid = threadIdx.x, l = tid & 63, w = tid >> 6;
  const int lrow = l & 15, hi = l >> 4;
  char* Pb = reinterpret_cast<char*>(&Plds[w][0]);

  // Q fragments (B-operand): lane holds Q[q = w*32 + qt*16 + lrow][d = ks*32 + hi*8 ..+7]
  short8 qf[2][2];
#pragma unroll
  for (int qt = 0; qt < 2; ++qt)
#pragma unroll
    for (int ks = 0; ks < 2; ++ks)
      qf[qt][ks] = *reinterpret_cast<const short8*>(qp + (size_t)(w * 32 + qt * 16 + lrow) * HD + ks * 32 + hi * 8);

  f32x4 acc[2][4] = {};
  float mreg[2] = {-1e30f, -1e30f};
  float lsum[2] = {0.0f, 0.0f};

  for (int kv = 0; kv < TSEQ / 64; ++kv) {
    // mask words (per lane: k = kt*16 + hi*4 + r)
    i32x4 mi[4];
#pragma unroll
    for (int kt = 0; kt < 4; ++kt)
      mi[kt] = *reinterpret_cast<const i32x4*>(mp + kv * 64 + kt * 16 + hi * 4);

    // K fragments (A-operand): K[t = kv*64 + kt*16 + lrow][d = ks*32 + hi*8..]
    short8 kf[2][4];
#pragma unroll
    for (int ks = 0; ks < 2; ++ks)
#pragma unroll
      for (int kt = 0; kt < 4; ++kt)
        kf[ks][kt] = *reinterpret_cast<const short8*>(
            kp + (size_t)(kv * 64 + kt * 16 + lrow) * HD + ks * 32 + hi * 8);

    // ---- S^T = K Q^T : st[kt][qt], S^T[k = kt*16 + hi*4 + r][q = qt*16 + lrow] ----
    f32x4 st[4][2] = {};
#pragma unroll
    for (int ks = 0; ks < 2; ++ks)
#pragma unroll
      for (int kt = 0; kt < 4; ++kt)
#pragma unroll
        for (int qt = 0; qt < 2; ++qt)
          st[kt][qt] = __builtin_amdgcn_mfma_f32_16x16x32_bf16(kf[ks][kt], qf[qt][ks], st[kt][qt], 0, 0, 0);

    // V^T fragments (B-operand for PV): V^T[d = dc*16 + lrow][k = ks*32 + hi*8..]
    // issued here so L2 latency hides under softmax
    short8 vf[2][4];
#pragma unroll
    for (int ks = 0; ks < 2; ++ks)
#pragma unroll
      for (int dc = 0; dc < 4; ++dc)
        vf[ks][dc] = *reinterpret_cast<const short8*>(
            vtp + (size_t)(dc * 16 + lrow) * TSEQ + kv * 64 + ks * 32 + hi * 8);

    // additive mask (-inf semantics, matches reference exactly)
#pragma unroll
    for (int kt = 0; kt < 4; ++kt) {
      f32x4 ma;
#pragma unroll
      for (int r = 0; r < 4; ++r) ma[r] = mi[kt][r] ? -1e30f : 0.0f;
#pragma unroll
      for (int qt = 0; qt < 2; ++qt) st[kt][qt] += ma;
    }

    // ---- online softmax (log2 domain; per lane: q = qt*16+lrow, 16 k in regs) ----
    float scl[2];
#pragma unroll
    for (int qt = 0; qt < 2; ++qt) {
      f32x4 mm;
#pragma unroll
      for (int r = 0; r < 4; ++r)
        mm[r] = fmaxf(fmaxf(st[0][qt][r], st[1][qt][r]), fmaxf(st[2][qt][r], st[3][qt][r]));
      float mx = fmaxf(fmaxf(mm[0], mm[1]), fmaxf(mm[2], mm[3]));
      mx = fmaxf(mx, __shfl_xor(mx, 16));
      mx = fmaxf(mx, __shfl_xor(mx, 32));
      float mnew = fmaxf(mreg[qt], mx);
      scl[qt] = __builtin_amdgcn_exp2f(mreg[qt] - mnew);
      mreg[qt] = mnew;
#pragma unroll
      for (int kt = 0; kt < 4; ++kt)
#pragma unroll
        for (int r = 0; r < 4; ++r)
          st[kt][qt][r] = __builtin_amdgcn_exp2f(st[kt][qt][r] - mnew);
      f32x4 sv = (st[0][qt] + st[1][qt]) + (st[2][qt] + st[3][qt]);
      float ps = (sv[0] + sv[1]) + (sv[2] + sv[3]);
      ps += __shfl_xor(ps, 16);
      ps += __shfl_xor(ps, 32);
      lsum[qt] = lsum[qt] * scl[qt] + ps;
      slds[w][qt * 16 + lrow] = scl[qt];   // broadcast scale to acc layout (wave-local)
    }

    // ---- pack P (bf16) -> per-wave LDS, swizzled 8B slots ----
#pragma unroll
    for (int qt = 0; qt < 2; ++qt) {
      int q = qt * 16 + lrow;
#pragma unroll
      for (int kt = 0; kt < 4; ++kt) {
        uint2 pw;
        pw.x = pk2(st[kt][qt][0], st[kt][qt][1]);
        pw.y = pk2(st[kt][qt][2], st[kt][qt][3]);
        *reinterpret_cast<uint2*>(
            Pb + q * 128 + ((((kt * 2 + (hi >> 1)) ^ (q & 7)) & 7) << 4) + ((hi & 1) << 3)) = pw;
      }
    }

    // ---- rescale acc (acc layout: q = qt*16 + hi*4 + r) ----
#pragma unroll
    for (int qt = 0; qt < 2; ++qt)
#pragma unroll
      for (int r = 0; r < 4; ++r) {
        float sc = slds[w][qt * 16 + hi * 4 + r];
#pragma unroll
        for (int dc = 0; dc < 4; ++dc) acc[qt][dc][r] *= sc;
      }

    // ---- O += P V ----
#pragma unroll
    for (int ks = 0; ks < 2; ++ks) {
      short8 pa[2];
#pragma unroll
      for (int qt = 0; qt < 2; ++qt) {
        int q = qt * 16 + lrow;
        pa[qt] = *reinterpret_cast<const short8*>(Pb + q * 128 + (((ks * 4 + hi) ^ (q & 7)) << 4));
      }
#pragma unroll
      for (int qt = 0; qt < 2; ++qt)
#pragma unroll
        for (int dc = 0; dc < 4; ++dc)
          acc[qt][dc] = __builtin_amdgcn_mfma_f32_16x16x32_bf16(pa[qt], vf[ks][dc], acc[qt][dc], 0, 0, 0);
    }
  }

  // ---- epilogue: O /= lsum, write c (B,T,H) bf16 ----
#pragma unroll
  for (int qt = 0; qt < 2; ++qt) slds[w][qt * 16 + lrow] = lsum[qt];
#pragma unroll
  for (int qt = 0; qt < 2; ++qt) {
#pragma unroll
    for (int r = 0; r < 4; ++r) {
      float inv = 1.0f / slds[w][qt * 16 + hi * 4 + r];
      int t = qb * 128 + w * 32 + qt * 16 + hi * 4 + r;
#pragma unroll
      for (int dc = 0; dc < 4; ++dc) {
        int col = head * HD + dc * 16 + lrow;
        c[((size_t)(b * TSEQ) + t) * HDIM + col] = f2bf(acc[qt][dc][r] * inv);
      }
    }
  }
}

extern "C" void kernel_launch(void* const* d_in, const int* in_sizes, int n_in,
                              void* d_out, int out_size, void* d_ws, size_t ws_size,
                              hipStream_t stream) {
  const float* x   = (const float*)d_in[0];
  const int* mask  = (const int*)d_in[1];
  const float* lng = (const float*)d_in[2];
  const float* lnb = (const float*)d_in[3];
  const float* wq  = (const float*)d_in[4];
  const float* bq  = (const float*)d_in[5];
  const float* wk  = (const float*)d_in[6];
  const float* bk  = (const float*)d_in[7];
  const float* wv  = (const float*)d_in[8];
  const float* bv  = (const float*)d_in[9];
  const float* wo  = (const float*)d_in[10];
  const float* bo  = (const float*)d_in[11];
  float* out = (float*)d_out;
  char* ws = (char*)d_ws;

  unsigned short* h   = (unsigned short*)ws;                       // 16MB (B*T*H bf16)
  unsigned short* wbf = (unsigned short*)(ws + (16u << 20));       // 8MB (4 weights bf16)
  unsigned short* qs  = (unsigned short*)(ws + (24u << 20));       // 16MB
  unsigned short* ksb = (unsigned short*)(ws + (40u << 20));       // 16MB
  unsigned short* vt  = (unsigned short*)(ws + (56u << 20));       // 16MB (V^T: B,NH,HD,T)
  unsigned short* c   = h;  // h dead after QKV GEMM

  convert_w<<<4096, 256, 0, stream>>>(wq, wk, wv, wo, wbf);
  ln_kernel<<<BATCH * TSEQ, 256, 0, stream>>>(x, lng, lnb, h);
  gemm_k<0><<<dim3(8, 64, 3), 256, 0, stream>>>(h, wbf, bq, bk, bv, qs, ksb, vt, nullptr, nullptr);
  attn_kernel<<<dim3(TSEQ / 128, NH, BATCH), 256, 0, stream>>>(qs, ksb, vt, mask, c);
  gemm_k<1><<<dim3(8, 64, 1), 256, 0, stream>>>(c, wbf + (size_t)3 * HDIM * HDIM, bo, nullptr, nullptr,
                                                nullptr, nullptr, nullptr, x, out);
}

// Round 4
// 323.384 us; speedup vs baseline: 1.1540x; 1.1540x over previous
//
#include <hip/hip_runtime.h>
#include <hip/hip_bf16.h>

typedef short short8 __attribute__((ext_vector_type(8)));
typedef float f32x4 __attribute__((ext_vector_type(4)));

#define HDIM 1024
#define TSEQ 2048
#define BATCH 4
#define NH 16
#define HD 64
#define SCALE_Q 0.18033688011f   // 0.125 * log2(e)

__device__ __forceinline__ unsigned short f2bf(float f) {
  union { float f; unsigned u; } x; x.f = f;
  unsigned r = x.u + 0x7fffu + ((x.u >> 16) & 1u);
  return (unsigned short)(r >> 16);
}

__device__ __forceinline__ unsigned pk2(float a, float b) {
  __hip_bfloat162 h2 = __float22bfloat162_rn(float2{a, b});
  union { __hip_bfloat162 h; unsigned u; } u2; u2.h = h2;
  return u2.u;
}

// 16B-slot XOR swizzle within a 128B row (8 slots)
__device__ __forceinline__ int swz(int row, int slot) { return slot ^ (row & 7); }

// ---------------- weight fp32 -> bf16 ----------------
__global__ __launch_bounds__(256) void convert_w(
    const float* __restrict__ wq, const float* __restrict__ wk,
    const float* __restrict__ wv, const float* __restrict__ wo,
    unsigned short* __restrict__ out) {
  size_t i = ((size_t)blockIdx.x * 256 + threadIdx.x) * 4;   // 4 elems/thread
  int which = (int)(i >> 20);                                // H*H = 2^20
  const float* src = which == 0 ? wq : which == 1 ? wk : which == 2 ? wv : wo;
  size_t off = i & ((1u << 20) - 1);
  float4 v = *reinterpret_cast<const float4*>(src + off);
  unsigned lo = (unsigned)f2bf(v.x) | ((unsigned)f2bf(v.y) << 16);
  unsigned hi = (unsigned)f2bf(v.z) | ((unsigned)f2bf(v.w) << 16);
  uint2 o; o.x = lo; o.y = hi;
  *reinterpret_cast<uint2*>(out + i) = o;
}

// ---------------- LayerNorm -> bf16 ----------------
__global__ __launch_bounds__(256) void ln_kernel(
    const float* __restrict__ x, const float* __restrict__ g,
    const float* __restrict__ bta, unsigned short* __restrict__ h) {
  int row = blockIdx.x;
  int tid = threadIdx.x;
  const float* xr = x + (size_t)row * HDIM;
  float4 v = *reinterpret_cast<const float4*>(xr + tid * 4);
  float s = v.x + v.y + v.z + v.w;
  float sq = v.x * v.x + v.y * v.y + v.z * v.z + v.w * v.w;
  for (int m = 32; m; m >>= 1) { s += __shfl_xor(s, m); sq += __shfl_xor(sq, m); }
  __shared__ float red[8];
  int w = tid >> 6, l = tid & 63;
  if (l == 0) { red[w] = s; red[4 + w] = sq; }
  __syncthreads();
  s = red[0] + red[1] + red[2] + red[3];
  sq = red[4] + red[5] + red[6] + red[7];
  float mu = s * (1.0f / HDIM);
  float var = sq * (1.0f / HDIM) - mu * mu;
  float inv = rsqrtf(var + 1e-5f);
  float4 gv = *reinterpret_cast<const float4*>(g + tid * 4);
  float4 bv = *reinterpret_cast<const float4*>(bta + tid * 4);
  unsigned short o0 = f2bf((v.x - mu) * inv * gv.x + bv.x);
  unsigned short o1 = f2bf((v.y - mu) * inv * gv.y + bv.y);
  unsigned short o2 = f2bf((v.z - mu) * inv * gv.z + bv.z);
  unsigned short o3 = f2bf((v.w - mu) * inv * gv.w + bv.w);
  uint2 o; o.x = (unsigned)o0 | ((unsigned)o1 << 16); o.y = (unsigned)o2 | ((unsigned)o3 << 16);
  *reinterpret_cast<uint2*>(h + (size_t)row * HDIM + tid * 4) = o;
}

// ---------------- GEMM: C = A(bf16 MxK) * W^T(bf16 NxK) + bias ----------------
// MODE 0: QKV. z=0: Q*(0.125*log2e) -> (B,NH,T,HD); z=1: K -> (B,NH,T,HD);
//         z=2: V^T -> (B,NH,HD,T)
// MODE 1: out-proj -> fp32 out = acc + bias + xres
template <int MODE>
__global__ __launch_bounds__(256) void gemm_k(
    const unsigned short* __restrict__ A, const unsigned short* __restrict__ Wb,
    const float* __restrict__ b0, const float* __restrict__ b1, const float* __restrict__ b2,
    unsigned short* __restrict__ o0, unsigned short* __restrict__ o1, unsigned short* __restrict__ o2,
    const float* __restrict__ xres, float* __restrict__ outf) {
  __shared__ __align__(16) unsigned short Alds[128 * 64];
  __shared__ __align__(16) unsigned short Wlds[128 * 64];
  const int z = blockIdx.z;
  const unsigned short* Wp = Wb + (size_t)z * HDIM * HDIM;
  const float* bias = (z == 0) ? b0 : (z == 1) ? b1 : b2;
  unsigned short* obf = (z == 0) ? o0 : (z == 1) ? o1 : o2;
  const int tid = threadIdx.x;
  const int l = tid & 63, w = tid >> 6;
  const int wr = (w >> 1) * 64, wc = (w & 1) * 64;
  const int bn = blockIdx.x, bm = blockIdx.y;
  const int lrow = l & 15, lk = l >> 4;
  f32x4 acc[4][4] = {};
  for (int kt = 0; kt < 16; ++kt) {
    __syncthreads();
#pragma unroll
    for (int p = 0; p < 4; ++p) {
      int flat = p * 256 + tid;           // 1024 chunks of 16B
      int row = flat >> 3, slot = flat & 7;
      uint4 av = *reinterpret_cast<const uint4*>(A + (size_t)(bm * 128 + row) * HDIM + kt * 64 + slot * 8);
      *reinterpret_cast<uint4*>(reinterpret_cast<char*>(Alds) + row * 128 + swz(row, slot) * 16) = av;
      uint4 wv = *reinterpret_cast<const uint4*>(Wp + (size_t)(bn * 128 + row) * HDIM + kt * 64 + slot * 8);
      *reinterpret_cast<uint4*>(reinterpret_cast<char*>(Wlds) + row * 128 + swz(row, slot) * 16) = wv;
    }
    __syncthreads();
#pragma unroll
    for (int ks = 0; ks < 2; ++ks) {
      short8 af[4], bfr[4];
#pragma unroll
      for (int rt = 0; rt < 4; ++rt) {
        int row = wr + rt * 16 + lrow;
        af[rt] = *reinterpret_cast<const short8*>(reinterpret_cast<char*>(Alds) + row * 128 + swz(row, ks * 4 + lk) * 16);
      }
#pragma unroll
      for (int ct = 0; ct < 4; ++ct) {
        int row = wc + ct * 16 + lrow;
        bfr[ct] = *reinterpret_cast<const short8*>(reinterpret_cast<char*>(Wlds) + row * 128 + swz(row, ks * 4 + lk) * 16);
      }
#pragma unroll
      for (int rt = 0; rt < 4; ++rt)
#pragma unroll
        for (int ct = 0; ct < 4; ++ct)
          acc[rt][ct] = __builtin_amdgcn_mfma_f32_16x16x32_bf16(af[rt], bfr[ct], acc[rt][ct], 0, 0, 0);
    }
  }
#pragma unroll
  for (int rt = 0; rt < 4; ++rt) {
#pragma unroll
    for (int ct = 0; ct < 4; ++ct) {
      int ncol = bn * 128 + wc + ct * 16 + lrow;
      float bv = bias[ncol];
      if (MODE == 0 && z == 2) {
        // V^T: (B,NH,HD,T); 4 consecutive t -> one 8B packed store
        int mrow0 = bm * 128 + wr + rt * 16 + lk * 4;
        int bb = mrow0 >> 11, t0 = mrow0 & (TSEQ - 1);
        int head = ncol >> 6, d = ncol & 63;
        uint2 pw;
        pw.x = pk2(acc[rt][ct][0] + bv, acc[rt][ct][1] + bv);
        pw.y = pk2(acc[rt][ct][2] + bv, acc[rt][ct][3] + bv);
        *reinterpret_cast<uint2*>(obf + ((size_t)(bb * NH + head) * HD + d) * TSEQ + t0) = pw;
      } else {
#pragma unroll
        for (int r = 0; r < 4; ++r) {
          int mrow = bm * 128 + wr + rt * 16 + lk * 4 + r;
          float val = acc[rt][ct][r] + bv;
          if (MODE == 0) {
            if (z == 0) val *= SCALE_Q;       // fold 1/sqrt(HEAD) * log2(e) into Q
            int bb = mrow >> 11, t = mrow & (TSEQ - 1);
            int head = ncol >> 6, d = ncol & 63;
            obf[((size_t)(bb * NH + head) * TSEQ + t) * HD + d] = f2bf(val);
          } else {
            size_t idx = (size_t)mrow * HDIM + ncol;
            outf[idx] = val + xres[idx];
          }
        }
      }
    }
  }
}

// ---------------- flash attention: swapped-QK^T + LDS staging + reg-prefetch ----
// grid: (T/128, NH, B), block 256 (4 waves, each 32 q rows), KVBLK=64
__global__ __launch_bounds__(256) void attn_kernel(
    const unsigned short* __restrict__ q_s, const unsigned short* __restrict__ k_s,
    const unsigned short* __restrict__ vt_s, const int* __restrict__ mask,
    unsigned short* __restrict__ c) {
  __shared__ __align__(16) unsigned short Klds[64 * 64];   // K tile, row k, swz
  __shared__ __align__(16) unsigned short Vlds[64 * 64];   // V^T tile, row d, swz
  __shared__ __align__(16) unsigned short Plds[4][2048];   // per-wave P
  __shared__ __align__(16) float mzlds[64];
  __shared__ float slds[4][32];
  const int b = blockIdx.z, head = blockIdx.y, qb = blockIdx.x;
  const unsigned short* qp = q_s + ((size_t)(b * NH + head) * TSEQ + qb * 128) * HD;
  const unsigned short* kp = k_s + (size_t)(b * NH + head) * TSEQ * HD;
  const unsigned short* vtp = vt_s + (size_t)(b * NH + head) * HD * TSEQ;
  const int* mp = mask + b * TSEQ;
  const int tid = threadIdx.x, l = tid & 63, w = tid >> 6;
  const int lrow = l & 15, hi = l >> 4;
  char* Kb = reinterpret_cast<char*>(Klds);
  char* Vb = reinterpret_cast<char*>(Vlds);
  char* Pb = reinterpret_cast<char*>(&Plds[w][0]);
  const int rr = tid >> 3, ss = tid & 7;    // staging coords: rows rr/rr+32, slot ss

  // Q fragments (B-operand): lane holds Q[q = w*32 + qt*16 + lrow][d = ks*32 + hi*8 ..+7]
  short8 qf[2][2];
#pragma unroll
  for (int qt = 0; qt < 2; ++qt)
#pragma unroll
    for (int ks = 0; ks < 2; ++ks)
      qf[qt][ks] = *reinterpret_cast<const short8*>(qp + (size_t)(w * 32 + qt * 16 + lrow) * HD + ks * 32 + hi * 8);

  f32x4 acc[2][4] = {};
  float mreg[2] = {-1e30f, -1e30f};
  float lsum[2] = {0.0f, 0.0f};

  uint4 kpre[2], vpre[2];
  float mpre = 0.0f;

  auto ISSUE = [&](int kv) {
#pragma unroll
    for (int p = 0; p < 2; ++p) {
      int row = p * 32 + rr;
      kpre[p] = *reinterpret_cast<const uint4*>(kp + (size_t)(kv * 64 + row) * HD + ss * 8);
      vpre[p] = *reinterpret_cast<const uint4*>(vtp + (size_t)row * TSEQ + kv * 64 + ss * 8);
    }
    if (tid < 64) mpre = mp[kv * 64 + tid] ? -1e30f : 0.0f;
  };

  ISSUE(0);

  for (int kv = 0; kv < TSEQ / 64; ++kv) {
    __syncthreads();   // all waves done reading previous tile
    // ---- write staged tile to LDS (pure b128, swizzled) ----
#pragma unroll
    for (int p = 0; p < 2; ++p) {
      int row = p * 32 + rr;
      *reinterpret_cast<uint4*>(Kb + row * 128 + ((ss ^ (row & 7)) << 4)) = kpre[p];
      *reinterpret_cast<uint4*>(Vb + row * 128 + ((ss ^ (row & 7)) << 4)) = vpre[p];
    }
    if (tid < 64) mzlds[tid] = mpre;
    if (kv + 1 < TSEQ / 64) ISSUE(kv + 1);   // prefetch next tile under this compute
    __syncthreads();   // tile ready

    // ---- S^T = K Q^T : st[kt][qt], S^T[k = kt*16 + hi*4 + r][q = qt*16 + lrow] ----
    f32x4 st[4][2] = {};
#pragma unroll
    for (int ks = 0; ks < 2; ++ks) {
      short8 kf[4];
#pragma unroll
      for (int kt = 0; kt < 4; ++kt) {
        int row = kt * 16 + lrow;
        kf[kt] = *reinterpret_cast<const short8*>(Kb + row * 128 + (((ks * 4 + hi) ^ (row & 7)) << 4));
      }
#pragma unroll
      for (int kt = 0; kt < 4; ++kt)
#pragma unroll
        for (int qt = 0; qt < 2; ++qt)
          st[kt][qt] = __builtin_amdgcn_mfma_f32_16x16x32_bf16(kf[kt], qf[qt][ks], st[kt][qt], 0, 0, 0);
    }

    // additive mask (log2-domain scores; matches reference -inf semantics)
    float4 mz[4];
#pragma unroll
    for (int kt = 0; kt < 4; ++kt)
      mz[kt] = *reinterpret_cast<const float4*>(&mzlds[kt * 16 + hi * 4]);
#pragma unroll
    for (int kt = 0; kt < 4; ++kt) {
      float* mzp = reinterpret_cast<float*>(&mz[kt]);
#pragma unroll
      for (int qt = 0; qt < 2; ++qt)
#pragma unroll
        for (int r = 0; r < 4; ++r) st[kt][qt][r] += mzp[r];
    }

    // ---- online softmax (exp2 domain; per lane: q = qt*16+lrow, 16 k in regs) ----
    float scl[2];
#pragma unroll
    for (int qt = 0; qt < 2; ++qt) {
      f32x4 mm;
#pragma unroll
      for (int r = 0; r < 4; ++r)
        mm[r] = fmaxf(fmaxf(st[0][qt][r], st[1][qt][r]), fmaxf(st[2][qt][r], st[3][qt][r]));
      float mx = fmaxf(fmaxf(mm[0], mm[1]), fmaxf(mm[2], mm[3]));
      mx = fmaxf(mx, __shfl_xor(mx, 16));
      mx = fmaxf(mx, __shfl_xor(mx, 32));
      float mnew = fmaxf(mreg[qt], mx);
      scl[qt] = __builtin_amdgcn_exp2f(mreg[qt] - mnew);
      mreg[qt] = mnew;
#pragma unroll
      for (int kt = 0; kt < 4; ++kt)
#pragma unroll
        for (int r = 0; r < 4; ++r)
          st[kt][qt][r] = __builtin_amdgcn_exp2f(st[kt][qt][r] - mnew);
      f32x4 sv = (st[0][qt] + st[1][qt]) + (st[2][qt] + st[3][qt]);
      float ps = (sv[0] + sv[1]) + (sv[2] + sv[3]);
      ps += __shfl_xor(ps, 16);
      ps += __shfl_xor(ps, 32);
      lsum[qt] = lsum[qt] * scl[qt] + ps;
      slds[w][qt * 16 + lrow] = scl[qt];   // broadcast scale to acc layout (wave-local)
    }

    // ---- pack P (bf16) -> per-wave LDS, swizzled 8B slots ----
#pragma unroll
    for (int qt = 0; qt < 2; ++qt) {
      int q = qt * 16 + lrow;
#pragma unroll
      for (int kt = 0; kt < 4; ++kt) {
        uint2 pw;
        pw.x = pk2(st[kt][qt][0], st[kt][qt][1]);
        pw.y = pk2(st[kt][qt][2], st[kt][qt][3]);
        *reinterpret_cast<uint2*>(
            Pb + q * 128 + ((((kt * 2 + (hi >> 1)) ^ (q & 7)) & 7) << 4) + ((hi & 1) << 3)) = pw;
      }
    }

    // ---- rescale acc (acc layout: q = qt*16 + hi*4 + r) ----
#pragma unroll
    for (int qt = 0; qt < 2; ++qt)
#pragma unroll
      for (int r = 0; r < 4; ++r) {
        float sc = slds[w][qt * 16 + hi * 4 + r];
#pragma unroll
        for (int dc = 0; dc < 4; ++dc) acc[qt][dc][r] *= sc;
      }

    // ---- O += P V ----
#pragma unroll
    for (int ks = 0; ks < 2; ++ks) {
      short8 pa[2], vf[4];
#pragma unroll
      for (int qt = 0; qt < 2; ++qt) {
        int q = qt * 16 + lrow;
        pa[qt] = *reinterpret_cast<const short8*>(Pb + q * 128 + (((ks * 4 + hi) ^ (q & 7)) << 4));
      }
#pragma unroll
      for (int dc = 0; dc < 4; ++dc) {
        int d = dc * 16 + lrow;
        vf[dc] = *reinterpret_cast<const short8*>(Vb + d * 128 + (((ks * 4 + hi) ^ (d & 7)) << 4));
      }
#pragma unroll
      for (int qt = 0; qt < 2; ++qt)
#pragma unroll
        for (int dc = 0; dc < 4; ++dc)
          acc[qt][dc] = __builtin_amdgcn_mfma_f32_16x16x32_bf16(pa[qt], vf[dc], acc[qt][dc], 0, 0, 0);
    }
  }

  // ---- epilogue: O /= lsum, write c (B,T,H) bf16 ----
#pragma unroll
  for (int qt = 0; qt < 2; ++qt) slds[w][qt * 16 + lrow] = lsum[qt];
#pragma unroll
  for (int qt = 0; qt < 2; ++qt) {
#pragma unroll
    for (int r = 0; r < 4; ++r) {
      float inv = 1.0f / slds[w][qt * 16 + hi * 4 + r];
      int t = qb * 128 + w * 32 + qt * 16 + hi * 4 + r;
#pragma unroll
      for (int dc = 0; dc < 4; ++dc) {
        int col = head * HD + dc * 16 + lrow;
        c[((size_t)(b * TSEQ) + t) * HDIM + col] = f2bf(acc[qt][dc][r] * inv);
      }
    }
  }
}

extern "C" void kernel_launch(void* const* d_in, const int* in_sizes, int n_in,
                              void* d_out, int out_size, void* d_ws, size_t ws_size,
                              hipStream_t stream) {
  const float* x   = (const float*)d_in[0];
  const int* mask  = (const int*)d_in[1];
  const float* lng = (const float*)d_in[2];
  const float* lnb = (const float*)d_in[3];
  const float* wq  = (const float*)d_in[4];
  const float* bq  = (const float*)d_in[5];
  const float* wk  = (const float*)d_in[6];
  const float* bk  = (const float*)d_in[7];
  const float* wv  = (const float*)d_in[8];
  const float* bv  = (const float*)d_in[9];
  const float* wo  = (const float*)d_in[10];
  const float* bo  = (const float*)d_in[11];
  float* out = (float*)d_out;
  char* ws = (char*)d_ws;

  unsigned short* h   = (unsigned short*)ws;                       // 16MB (B*T*H bf16)
  unsigned short* wbf = (unsigned short*)(ws + (16u << 20));       // 8MB (4 weights bf16)
  unsigned short* qs  = (unsigned short*)(ws + (24u << 20));       // 16MB
  unsigned short* ksb = (unsigned short*)(ws + (40u << 20));       // 16MB
  unsigned short* vt  = (unsigned short*)(ws + (56u << 20));       // 16MB (V^T: B,NH,HD,T)
  unsigned short* c   = h;  // h dead after QKV GEMM

  convert_w<<<4096, 256, 0, stream>>>(wq, wk, wv, wo, wbf);
  ln_kernel<<<BATCH * TSEQ, 256, 0, stream>>>(x, lng, lnb, h);
  gemm_k<0><<<dim3(8, 64, 3), 256, 0, stream>>>(h, wbf, bq, bk, bv, qs, ksb, vt, nullptr, nullptr);
  attn_kernel<<<dim3(TSEQ / 128, NH, BATCH), 256, 0, stream>>>(qs, ksb, vt, mask, c);
  gemm_k<1><<<dim3(8, 64, 1), 256, 0, stream>>>(c, wbf + (size_t)3 * HDIM * HDIM, bo, nullptr, nullptr,
                                                nullptr, nullptr, nullptr, x, out);
}

// Round 5
// 290.965 us; speedup vs baseline: 1.2826x; 1.1114x over previous
//
#include <hip/hip_runtime.h>
#include <hip/hip_bf16.h>

typedef short short8 __attribute__((ext_vector_type(8)));
typedef float f32x4 __attribute__((ext_vector_type(4)));
typedef int i32x4 __attribute__((ext_vector_type(4)));

#define HDIM 1024
#define TSEQ 2048
#define BATCH 4
#define NH 16
#define HD 64
#define SCALE_Q 0.18033688011f   // 0.125 * log2(e)

__device__ __forceinline__ unsigned short f2bf(float f) {
  union { float f; unsigned u; } x; x.f = f;
  unsigned r = x.u + 0x7fffu + ((x.u >> 16) & 1u);
  return (unsigned short)(r >> 16);
}

__device__ __forceinline__ unsigned pk2(float a, float b) {
  __hip_bfloat162 h2 = __float22bfloat162_rn(float2{a, b});
  union { __hip_bfloat162 h; unsigned u; } u2; u2.h = h2;
  return u2.u;
}

// 16B-slot XOR swizzle within a 128B row (8 slots)
__device__ __forceinline__ int swz(int row, int slot) { return slot ^ (row & 7); }

// async global->LDS DMA, 16B per lane; LDS dest = uniform base + lane*16
typedef const __attribute__((address_space(1))) void* gas_ptr;
typedef __attribute__((address_space(3))) void* las_ptr;
__device__ __forceinline__ void gl2lds16(const void* g, void* l) {
  __builtin_amdgcn_global_load_lds((gas_ptr)g, (las_ptr)l, 16, 0, 0);
}

// ---------------- weight fp32 -> bf16 ----------------
__global__ __launch_bounds__(256) void convert_w(
    const float* __restrict__ wq, const float* __restrict__ wk,
    const float* __restrict__ wv, const float* __restrict__ wo,
    unsigned short* __restrict__ out) {
  size_t i = ((size_t)blockIdx.x * 256 + threadIdx.x) * 4;   // 4 elems/thread
  int which = (int)(i >> 20);                                // H*H = 2^20
  const float* src = which == 0 ? wq : which == 1 ? wk : which == 2 ? wv : wo;
  size_t off = i & ((1u << 20) - 1);
  float4 v = *reinterpret_cast<const float4*>(src + off);
  unsigned lo = (unsigned)f2bf(v.x) | ((unsigned)f2bf(v.y) << 16);
  unsigned hi = (unsigned)f2bf(v.z) | ((unsigned)f2bf(v.w) << 16);
  uint2 o; o.x = lo; o.y = hi;
  *reinterpret_cast<uint2*>(out + i) = o;
}

// ---------------- LayerNorm -> bf16 ----------------
__global__ __launch_bounds__(256) void ln_kernel(
    const float* __restrict__ x, const float* __restrict__ g,
    const float* __restrict__ bta, unsigned short* __restrict__ h) {
  int row = blockIdx.x;
  int tid = threadIdx.x;
  const float* xr = x + (size_t)row * HDIM;
  float4 v = *reinterpret_cast<const float4*>(xr + tid * 4);
  float s = v.x + v.y + v.z + v.w;
  float sq = v.x * v.x + v.y * v.y + v.z * v.z + v.w * v.w;
  for (int m = 32; m; m >>= 1) { s += __shfl_xor(s, m); sq += __shfl_xor(sq, m); }
  __shared__ float red[8];
  int w = tid >> 6, l = tid & 63;
  if (l == 0) { red[w] = s; red[4 + w] = sq; }
  __syncthreads();
  s = red[0] + red[1] + red[2] + red[3];
  sq = red[4] + red[5] + red[6] + red[7];
  float mu = s * (1.0f / HDIM);
  float var = sq * (1.0f / HDIM) - mu * mu;
  float inv = rsqrtf(var + 1e-5f);
  float4 gv = *reinterpret_cast<const float4*>(g + tid * 4);
  float4 bv = *reinterpret_cast<const float4*>(bta + tid * 4);
  unsigned short o0 = f2bf((v.x - mu) * inv * gv.x + bv.x);
  unsigned short o1 = f2bf((v.y - mu) * inv * gv.y + bv.y);
  unsigned short o2 = f2bf((v.z - mu) * inv * gv.z + bv.z);
  unsigned short o3 = f2bf((v.w - mu) * inv * gv.w + bv.w);
  uint2 o; o.x = (unsigned)o0 | ((unsigned)o1 << 16); o.y = (unsigned)o2 | ((unsigned)o3 << 16);
  *reinterpret_cast<uint2*>(h + (size_t)row * HDIM + tid * 4) = o;
}

// ---------------- GEMM: C = A(bf16 MxK) * W^T(bf16 NxK) + bias ----------------
// Staging via global_load_lds with pre-swizzled global source (LDS dest linear).
// MODE 0: QKV. z=0: Q*(0.125*log2e) -> (B,NH,T,HD); z=1: K -> (B,NH,T,HD);
//         z=2: V^T -> (B,NH,HD,T)
// MODE 1: out-proj -> fp32 out = acc + bias + xres
template <int MODE>
__global__ __launch_bounds__(256) void gemm_k(
    const unsigned short* __restrict__ A, const unsigned short* __restrict__ Wb,
    const float* __restrict__ b0, const float* __restrict__ b1, const float* __restrict__ b2,
    unsigned short* __restrict__ o0, unsigned short* __restrict__ o1, unsigned short* __restrict__ o2,
    const float* __restrict__ xres, float* __restrict__ outf) {
  __shared__ __align__(16) unsigned short Alds[128 * 64];
  __shared__ __align__(16) unsigned short Wlds[128 * 64];
  const int z = blockIdx.z;
  const unsigned short* Wp = Wb + (size_t)z * HDIM * HDIM;
  const float* bias = (z == 0) ? b0 : (z == 1) ? b1 : b2;
  unsigned short* obf = (z == 0) ? o0 : (z == 1) ? o1 : o2;
  const int tid = threadIdx.x;
  const int l = tid & 63, w = tid >> 6;
  const int wr = (w >> 1) * 64, wc = (w & 1) * 64;
  const int bn = blockIdx.x, bm = blockIdx.y;
  const int lrow = l & 15, lk = l >> 4;
  const int sr = l >> 3;                       // lane's row-in-8 for DMA
  const int sslot = (l & 7) ^ (sr & 7);        // pre-swizzled source slot
  f32x4 acc[4][4] = {};
  for (int kt = 0; kt < 16; ++kt) {
    __syncthreads();
#pragma unroll
    for (int p = 0; p < 4; ++p) {
      int rb = w * 32 + p * 8;                 // uniform per wave
      int row = rb + sr;
      gl2lds16(A + (size_t)(bm * 128 + row) * HDIM + kt * 64 + sslot * 8, Alds + rb * 64);
      gl2lds16(Wp + (size_t)(bn * 128 + row) * HDIM + kt * 64 + sslot * 8, Wlds + rb * 64);
    }
    __syncthreads();
#pragma unroll
    for (int ks = 0; ks < 2; ++ks) {
      short8 af[4], bfr[4];
#pragma unroll
      for (int rt = 0; rt < 4; ++rt) {
        int row = wr + rt * 16 + lrow;
        af[rt] = *reinterpret_cast<const short8*>(reinterpret_cast<char*>(Alds) + row * 128 + swz(row, ks * 4 + lk) * 16);
      }
#pragma unroll
      for (int ct = 0; ct < 4; ++ct) {
        int row = wc + ct * 16 + lrow;
        bfr[ct] = *reinterpret_cast<const short8*>(reinterpret_cast<char*>(Wlds) + row * 128 + swz(row, ks * 4 + lk) * 16);
      }
#pragma unroll
      for (int rt = 0; rt < 4; ++rt)
#pragma unroll
        for (int ct = 0; ct < 4; ++ct)
          acc[rt][ct] = __builtin_amdgcn_mfma_f32_16x16x32_bf16(af[rt], bfr[ct], acc[rt][ct], 0, 0, 0);
    }
  }
#pragma unroll
  for (int rt = 0; rt < 4; ++rt) {
#pragma unroll
    for (int ct = 0; ct < 4; ++ct) {
      int ncol = bn * 128 + wc + ct * 16 + lrow;
      float bv = bias[ncol];
      if (MODE == 0 && z == 2) {
        // V^T: (B,NH,HD,T); 4 consecutive t -> one 8B packed store
        int mrow0 = bm * 128 + wr + rt * 16 + lk * 4;
        int bb = mrow0 >> 11, t0 = mrow0 & (TSEQ - 1);
        int head = ncol >> 6, d = ncol & 63;
        uint2 pw;
        pw.x = pk2(acc[rt][ct][0] + bv, acc[rt][ct][1] + bv);
        pw.y = pk2(acc[rt][ct][2] + bv, acc[rt][ct][3] + bv);
        *reinterpret_cast<uint2*>(obf + ((size_t)(bb * NH + head) * HD + d) * TSEQ + t0) = pw;
      } else {
#pragma unroll
        for (int r = 0; r < 4; ++r) {
          int mrow = bm * 128 + wr + rt * 16 + lk * 4 + r;
          float val = acc[rt][ct][r] + bv;
          if (MODE == 0) {
            if (z == 0) val *= SCALE_Q;       // fold 1/sqrt(HEAD) * log2(e) into Q
            int bb = mrow >> 11, t = mrow & (TSEQ - 1);
            int head = ncol >> 6, d = ncol & 63;
            obf[((size_t)(bb * NH + head) * TSEQ + t) * HD + d] = f2bf(val);
          } else {
            size_t idx = (size_t)mrow * HDIM + ncol;
            outf[idx] = val + xres[idx];
          }
        }
      }
    }
  }
}

// ---------------- flash attention: DMA staging, K-dbuf + V-JIT ----------------
// grid: (T/128, NH, B), block 256 (4 waves, each 32 q rows), KVBLK=64
// barrier(a): prev tile fully consumed -> issue V(kv) + K(kv+1) DMA
// barrier(b): after softmax -> V landed -> PV
__global__ __launch_bounds__(256) void attn_kernel(
    const unsigned short* __restrict__ q_s, const unsigned short* __restrict__ k_s,
    const unsigned short* __restrict__ vt_s, const int* __restrict__ mask,
    unsigned short* __restrict__ c) {
  __shared__ __align__(16) unsigned short Klds[2][64 * 64];  // 16KB dbuf
  __shared__ __align__(16) unsigned short Vlds[64 * 64];     // 8KB JIT
  __shared__ __align__(16) unsigned short Plds[4][1024];     // 2KB/wave, reused per 32-k half
  const int b = blockIdx.z, head = blockIdx.y, qb = blockIdx.x;
  const unsigned short* qp = q_s + ((size_t)(b * NH + head) * TSEQ + qb * 128) * HD;
  const unsigned short* kp = k_s + (size_t)(b * NH + head) * TSEQ * HD;
  const unsigned short* vtp = vt_s + (size_t)(b * NH + head) * HD * TSEQ;
  const int* mp = mask + b * TSEQ;
  const int tid = threadIdx.x, l = tid & 63, w = tid >> 6;
  const int lrow = l & 15, hi = l >> 4;
  char* Vb = reinterpret_cast<char*>(Vlds);
  char* Pb = reinterpret_cast<char*>(&Plds[w][0]);
  const int sr = l >> 3;                       // DMA: lane's row-in-8
  const int sslot = (l & 7) ^ (sr & 7);        // pre-swizzled source slot

  // Q fragments (B-operand): lane holds Q[q = w*32 + qt*16 + lrow][d = ks*32 + hi*8 ..+7]
  short8 qf[2][2];
#pragma unroll
  for (int qt = 0; qt < 2; ++qt)
#pragma unroll
    for (int ks = 0; ks < 2; ++ks)
      qf[qt][ks] = *reinterpret_cast<const short8*>(qp + (size_t)(w * 32 + qt * 16 + lrow) * HD + ks * 32 + hi * 8);

  f32x4 acc[2][4] = {};
  float mreg[2] = {-1e30f, -1e30f};
  float lsum[2] = {0.0f, 0.0f};

  auto KSTAGE = [&](int kv, int bi) {
#pragma unroll
    for (int p = 0; p < 2; ++p) {
      int rb = w * 16 + p * 8;                 // uniform per wave
      gl2lds16(kp + (size_t)(kv * 64 + rb + sr) * HD + sslot * 8, &Klds[bi][rb * 64]);
    }
  };
  auto VSTAGE = [&](int kv) {
#pragma unroll
    for (int p = 0; p < 2; ++p) {
      int rb = w * 16 + p * 8;                 // d rows
      gl2lds16(vtp + (size_t)(rb + sr) * TSEQ + kv * 64 + sslot * 8, Vlds + rb * 64);
    }
  };

  KSTAGE(0, 0);

  for (int kv = 0; kv < TSEQ / 64; ++kv) {
    const int bi = kv & 1;
    char* Kb = reinterpret_cast<char*>(&Klds[bi][0]);
    __syncthreads();                       // (a) prev tile consumed; K[bi] landed
    VSTAGE(kv);                            // V DMA hides under QK^T + softmax
    if (kv + 1 < TSEQ / 64) KSTAGE(kv + 1, bi ^ 1);

    // mask words (per lane: k = kt*16 + hi*4 + r), straight from global (L1-hit)
    i32x4 mi[4];
#pragma unroll
    for (int kt = 0; kt < 4; ++kt)
      mi[kt] = *reinterpret_cast<const i32x4*>(mp + kv * 64 + kt * 16 + hi * 4);

    // ---- S^T = K Q^T : st[kt][qt], S^T[k = kt*16 + hi*4 + r][q = qt*16 + lrow] ----
    f32x4 st[4][2] = {};
#pragma unroll
    for (int ks = 0; ks < 2; ++ks) {
      short8 kf[4];
#pragma unroll
      for (int kt = 0; kt < 4; ++kt) {
        int row = kt * 16 + lrow;
        kf[kt] = *reinterpret_cast<const short8*>(Kb + row * 128 + (((ks * 4 + hi) ^ (row & 7)) << 4));
      }
#pragma unroll
      for (int kt = 0; kt < 4; ++kt)
#pragma unroll
        for (int qt = 0; qt < 2; ++qt)
          st[kt][qt] = __builtin_amdgcn_mfma_f32_16x16x32_bf16(kf[kt], qf[qt][ks], st[kt][qt], 0, 0, 0);
    }

    // additive mask (log2-domain scores; matches reference -inf semantics)
#pragma unroll
    for (int kt = 0; kt < 4; ++kt) {
      f32x4 ma;
#pragma unroll
      for (int r = 0; r < 4; ++r) ma[r] = mi[kt][r] ? -1e30f : 0.0f;
#pragma unroll
      for (int qt = 0; qt < 2; ++qt) st[kt][qt] += ma;
    }

    // ---- online softmax (exp2 domain; per lane: q = qt*16+lrow, 16 k in regs) ----
    float scl[2];
#pragma unroll
    for (int qt = 0; qt < 2; ++qt) {
      f32x4 mm;
#pragma unroll
      for (int r = 0; r < 4; ++r)
        mm[r] = fmaxf(fmaxf(st[0][qt][r], st[1][qt][r]), fmaxf(st[2][qt][r], st[3][qt][r]));
      float mx = fmaxf(fmaxf(mm[0], mm[1]), fmaxf(mm[2], mm[3]));
      mx = fmaxf(mx, __shfl_xor(mx, 16));
      mx = fmaxf(mx, __shfl_xor(mx, 32));
      float mnew = fmaxf(mreg[qt], mx);
      scl[qt] = __builtin_amdgcn_exp2f(mreg[qt] - mnew);
      mreg[qt] = mnew;
#pragma unroll
      for (int kt = 0; kt < 4; ++kt)
#pragma unroll
        for (int r = 0; r < 4; ++r)
          st[kt][qt][r] = __builtin_amdgcn_exp2f(st[kt][qt][r] - mnew);
      f32x4 sv = (st[0][qt] + st[1][qt]) + (st[2][qt] + st[3][qt]);
      float ps = (sv[0] + sv[1]) + (sv[2] + sv[3]);
      ps += __shfl_xor(ps, 16);
      ps += __shfl_xor(ps, 32);
      lsum[qt] = lsum[qt] * scl[qt] + ps;
    }

    // ---- rescale acc; scl broadcast lrow-layout -> acc-layout via shuffle ----
#pragma unroll
    for (int qt = 0; qt < 2; ++qt)
#pragma unroll
      for (int r = 0; r < 4; ++r) {
        float sc = __shfl(scl[qt], hi * 4 + r);
#pragma unroll
        for (int dc = 0; dc < 4; ++dc) acc[qt][dc][r] *= sc;
      }

    __syncthreads();                       // (b) V landed
    // ---- PV in two 32-k halves; P region (2KB/wave) reused ----
#pragma unroll
    for (int hf = 0; hf < 2; ++hf) {
      // write P half: rows 64B, 4 slots of 16B, swizzle ^(q&3)
#pragma unroll
      for (int qt = 0; qt < 2; ++qt) {
        int q = qt * 16 + lrow;
#pragma unroll
        for (int k2 = 0; k2 < 2; ++k2) {
          int kt = hf * 2 + k2;
          uint2 pw;
          pw.x = pk2(st[kt][qt][0], st[kt][qt][1]);
          pw.y = pk2(st[kt][qt][2], st[kt][qt][3]);
          *reinterpret_cast<uint2*>(
              Pb + q * 64 + ((((k2 * 2 + (hi >> 1)) ^ (q & 3)) & 3) << 4) + ((hi & 1) << 3)) = pw;
        }
      }
      short8 pa[2], vf[4];
#pragma unroll
      for (int qt = 0; qt < 2; ++qt) {
        int q = qt * 16 + lrow;
        pa[qt] = *reinterpret_cast<const short8*>(Pb + q * 64 + (((hi ^ (q & 3)) & 3) << 4));
      }
#pragma unroll
      for (int dc = 0; dc < 4; ++dc) {
        int d = dc * 16 + lrow;
        vf[dc] = *reinterpret_cast<const short8*>(Vb + d * 128 + (((hf * 4 + hi) ^ (d & 7)) << 4));
      }
#pragma unroll
      for (int qt = 0; qt < 2; ++qt)
#pragma unroll
        for (int dc = 0; dc < 4; ++dc)
          acc[qt][dc] = __builtin_amdgcn_mfma_f32_16x16x32_bf16(pa[qt], vf[dc], acc[qt][dc], 0, 0, 0);
    }
  }

  // ---- epilogue: O /= lsum (shuffle broadcast), write c (B,T,H) bf16 ----
#pragma unroll
  for (int qt = 0; qt < 2; ++qt) {
#pragma unroll
    for (int r = 0; r < 4; ++r) {
      float inv = 1.0f / __shfl(lsum[qt], hi * 4 + r);
      int t = qb * 128 + w * 32 + qt * 16 + hi * 4 + r;
#pragma unroll
      for (int dc = 0; dc < 4; ++dc) {
        int col = head * HD + dc * 16 + lrow;
        c[((size_t)(b * TSEQ) + t) * HDIM + col] = f2bf(acc[qt][dc][r] * inv);
      }
    }
  }
}

extern "C" void kernel_launch(void* const* d_in, const int* in_sizes, int n_in,
                              void* d_out, int out_size, void* d_ws, size_t ws_size,
                              hipStream_t stream) {
  const float* x   = (const float*)d_in[0];
  const int* mask  = (const int*)d_in[1];
  const float* lng = (const float*)d_in[2];
  const float* lnb = (const float*)d_in[3];
  const float* wq  = (const float*)d_in[4];
  const float* bq  = (const float*)d_in[5];
  const float* wk  = (const float*)d_in[6];
  const float* bk  = (const float*)d_in[7];
  const float* wv  = (const float*)d_in[8];
  const float* bv  = (const float*)d_in[9];
  const float* wo  = (const float*)d_in[10];
  const float* bo  = (const float*)d_in[11];
  float* out = (float*)d_out;
  char* ws = (char*)d_ws;

  unsigned short* h   = (unsigned short*)ws;                       // 16MB (B*T*H bf16)
  unsigned short* wbf = (unsigned short*)(ws + (16u << 20));       // 8MB (4 weights bf16)
  unsigned short* qs  = (unsigned short*)(ws + (24u << 20));       // 16MB
  unsigned short* ksb = (unsigned short*)(ws + (40u << 20));       // 16MB
  unsigned short* vt  = (unsigned short*)(ws + (56u << 20));       // 16MB (V^T: B,NH,HD,T)
  unsigned short* c   = h;  // h dead after QKV GEMM

  convert_w<<<4096, 256, 0, stream>>>(wq, wk, wv, wo, wbf);
  ln_kernel<<<BATCH * TSEQ, 256, 0, stream>>>(x, lng, lnb, h);
  gemm_k<0><<<dim3(8, 64, 3), 256, 0, stream>>>(h, wbf, bq, bk, bv, qs, ksb, vt, nullptr, nullptr);
  attn_kernel<<<dim3(TSEQ / 128, NH, BATCH), 256, 0, stream>>>(qs, ksb, vt, mask, c);
  gemm_k<1><<<dim3(8, 64, 1), 256, 0, stream>>>(c, wbf + (size_t)3 * HDIM * HDIM, bo, nullptr, nullptr,
                                                nullptr, nullptr, nullptr, x, out);
}

// Round 6
// 259.963 us; speedup vs baseline: 1.4356x; 1.1193x over previous
//
#include <hip/hip_runtime.h>
#include <hip/hip_bf16.h>

typedef short short8 __attribute__((ext_vector_type(8)));
typedef float f32x4 __attribute__((ext_vector_type(4)));

#define HDIM 1024
#define TSEQ 2048
#define BATCH 4
#define NH 16
#define HD 64
#define SCALE_Q 0.18033688011f   // 0.125 * log2(e)

__device__ __forceinline__ unsigned short f2bf(float f) {
  union { float f; unsigned u; } x; x.f = f;
  unsigned r = x.u + 0x7fffu + ((x.u >> 16) & 1u);
  return (unsigned short)(r >> 16);
}

__device__ __forceinline__ unsigned pk2(float a, float b) {
  __hip_bfloat162 h2 = __float22bfloat162_rn(float2{a, b});
  union { __hip_bfloat162 h; unsigned u; } u2; u2.h = h2;
  return u2.u;
}

// 16B-slot XOR swizzle within a 128B row (8 slots)
__device__ __forceinline__ int swz(int row, int slot) { return slot ^ (row & 7); }

// async global->LDS DMA, 16B per lane; LDS dest = uniform base + lane*16
typedef const __attribute__((address_space(1))) void* gas_ptr;
typedef __attribute__((address_space(3))) void* las_ptr;
__device__ __forceinline__ void gl2lds16(const void* g, void* l) {
  __builtin_amdgcn_global_load_lds((gas_ptr)g, (las_ptr)l, 16, 0, 0);
}

// ---------------- weight fp32 -> bf16 ----------------
__global__ __launch_bounds__(256) void convert_w(
    const float* __restrict__ wq, const float* __restrict__ wk,
    const float* __restrict__ wv, const float* __restrict__ wo,
    unsigned short* __restrict__ out) {
  size_t i = ((size_t)blockIdx.x * 256 + threadIdx.x) * 4;   // 4 elems/thread
  int which = (int)(i >> 20);                                // H*H = 2^20
  const float* src = which == 0 ? wq : which == 1 ? wk : which == 2 ? wv : wo;
  size_t off = i & ((1u << 20) - 1);
  float4 v = *reinterpret_cast<const float4*>(src + off);
  unsigned lo = (unsigned)f2bf(v.x) | ((unsigned)f2bf(v.y) << 16);
  unsigned hi = (unsigned)f2bf(v.z) | ((unsigned)f2bf(v.w) << 16);
  uint2 o; o.x = lo; o.y = hi;
  *reinterpret_cast<uint2*>(out + i) = o;
}

// ---------------- mask int -> f32 additive bias ----------------
__global__ __launch_bounds__(256) void mask_bias(
    const int* __restrict__ m, float* __restrict__ o) {
  int i = blockIdx.x * 256 + threadIdx.x;
  o[i] = m[i] ? -1e30f : 0.0f;
}

// ---------------- LayerNorm -> bf16 ----------------
__global__ __launch_bounds__(256) void ln_kernel(
    const float* __restrict__ x, const float* __restrict__ g,
    const float* __restrict__ bta, unsigned short* __restrict__ h) {
  int row = blockIdx.x;
  int tid = threadIdx.x;
  const float* xr = x + (size_t)row * HDIM;
  float4 v = *reinterpret_cast<const float4*>(xr + tid * 4);
  float s = v.x + v.y + v.z + v.w;
  float sq = v.x * v.x + v.y * v.y + v.z * v.z + v.w * v.w;
  for (int m = 32; m; m >>= 1) { s += __shfl_xor(s, m); sq += __shfl_xor(sq, m); }
  __shared__ float red[8];
  int w = tid >> 6, l = tid & 63;
  if (l == 0) { red[w] = s; red[4 + w] = sq; }
  __syncthreads();
  s = red[0] + red[1] + red[2] + red[3];
  sq = red[4] + red[5] + red[6] + red[7];
  float mu = s * (1.0f / HDIM);
  float var = sq * (1.0f / HDIM) - mu * mu;
  float inv = rsqrtf(var + 1e-5f);
  float4 gv = *reinterpret_cast<const float4*>(g + tid * 4);
  float4 bv = *reinterpret_cast<const float4*>(bta + tid * 4);
  unsigned short o0 = f2bf((v.x - mu) * inv * gv.x + bv.x);
  unsigned short o1 = f2bf((v.y - mu) * inv * gv.y + bv.y);
  unsigned short o2 = f2bf((v.z - mu) * inv * gv.z + bv.z);
  unsigned short o3 = f2bf((v.w - mu) * inv * gv.w + bv.w);
  uint2 o; o.x = (unsigned)o0 | ((unsigned)o1 << 16); o.y = (unsigned)o2 | ((unsigned)o3 << 16);
  *reinterpret_cast<uint2*>(h + (size_t)row * HDIM + tid * 4) = o;
}

// ---------------- GEMM: C = A(bf16 MxK) * W^T(bf16 NxK) + bias ----------------
// Staging via global_load_lds with pre-swizzled global source (LDS dest linear).
// MODE 0: QKV. z=0: Q*(0.125*log2e) -> (B,NH,T,HD); z=1: K -> (B,NH,T,HD);
//         z=2: V^T -> (B,NH,HD,T)
// MODE 1: out-proj -> fp32 out = acc + bias + xres
template <int MODE>
__global__ __launch_bounds__(256) void gemm_k(
    const unsigned short* __restrict__ A, const unsigned short* __restrict__ Wb,
    const float* __restrict__ b0, const float* __restrict__ b1, const float* __restrict__ b2,
    unsigned short* __restrict__ o0, unsigned short* __restrict__ o1, unsigned short* __restrict__ o2,
    const float* __restrict__ xres, float* __restrict__ outf) {
  __shared__ __align__(16) unsigned short Alds[128 * 64];
  __shared__ __align__(16) unsigned short Wlds[128 * 64];
  const int z = blockIdx.z;
  const unsigned short* Wp = Wb + (size_t)z * HDIM * HDIM;
  const float* bias = (z == 0) ? b0 : (z == 1) ? b1 : b2;
  unsigned short* obf = (z == 0) ? o0 : (z == 1) ? o1 : o2;
  const int tid = threadIdx.x;
  const int l = tid & 63, w = tid >> 6;
  const int wr = (w >> 1) * 64, wc = (w & 1) * 64;
  const int bn = blockIdx.x, bm = blockIdx.y;
  const int lrow = l & 15, lk = l >> 4;
  const int sr = l >> 3;                       // lane's row-in-8 for DMA
  const int sslot = (l & 7) ^ (sr & 7);        // pre-swizzled source slot
  f32x4 acc[4][4] = {};
  for (int kt = 0; kt < 16; ++kt) {
    __syncthreads();
#pragma unroll
    for (int p = 0; p < 4; ++p) {
      int rb = w * 32 + p * 8;                 // uniform per wave
      int row = rb + sr;
      gl2lds16(A + (size_t)(bm * 128 + row) * HDIM + kt * 64 + sslot * 8, Alds + rb * 64);
      gl2lds16(Wp + (size_t)(bn * 128 + row) * HDIM + kt * 64 + sslot * 8, Wlds + rb * 64);
    }
    __syncthreads();
#pragma unroll
    for (int ks = 0; ks < 2; ++ks) {
      short8 af[4], bfr[4];
#pragma unroll
      for (int rt = 0; rt < 4; ++rt) {
        int row = wr + rt * 16 + lrow;
        af[rt] = *reinterpret_cast<const short8*>(reinterpret_cast<char*>(Alds) + row * 128 + swz(row, ks * 4 + lk) * 16);
      }
#pragma unroll
      for (int ct = 0; ct < 4; ++ct) {
        int row = wc + ct * 16 + lrow;
        bfr[ct] = *reinterpret_cast<const short8*>(reinterpret_cast<char*>(Wlds) + row * 128 + swz(row, ks * 4 + lk) * 16);
      }
#pragma unroll
      for (int rt = 0; rt < 4; ++rt)
#pragma unroll
        for (int ct = 0; ct < 4; ++ct)
          acc[rt][ct] = __builtin_amdgcn_mfma_f32_16x16x32_bf16(af[rt], bfr[ct], acc[rt][ct], 0, 0, 0);
    }
  }
#pragma unroll
  for (int rt = 0; rt < 4; ++rt) {
#pragma unroll
    for (int ct = 0; ct < 4; ++ct) {
      int ncol = bn * 128 + wc + ct * 16 + lrow;
      float bv = bias[ncol];
      if (MODE == 0 && z == 2) {
        // V^T: (B,NH,HD,T); 4 consecutive t -> one 8B packed store
        int mrow0 = bm * 128 + wr + rt * 16 + lk * 4;
        int bb = mrow0 >> 11, t0 = mrow0 & (TSEQ - 1);
        int head = ncol >> 6, d = ncol & 63;
        uint2 pw;
        pw.x = pk2(acc[rt][ct][0] + bv, acc[rt][ct][1] + bv);
        pw.y = pk2(acc[rt][ct][2] + bv, acc[rt][ct][3] + bv);
        *reinterpret_cast<uint2*>(obf + ((size_t)(bb * NH + head) * HD + d) * TSEQ + t0) = pw;
      } else {
#pragma unroll
        for (int r = 0; r < 4; ++r) {
          int mrow = bm * 128 + wr + rt * 16 + lk * 4 + r;
          float val = acc[rt][ct][r] + bv;
          if (MODE == 0) {
            if (z == 0) val *= SCALE_Q;       // fold 1/sqrt(HEAD) * log2(e) into Q
            int bb = mrow >> 11, t = mrow & (TSEQ - 1);
            int head = ncol >> 6, d = ncol & 63;
            obf[((size_t)(bb * NH + head) * TSEQ + t) * HD + d] = f2bf(val);
          } else {
            size_t idx = (size_t)mrow * HDIM + ncol;
            outf[idx] = val + xres[idx];
          }
        }
      }
    }
  }
}

// ---------------- flash attention: DMA staging, K-dbuf + V-JIT ----------------
// grid: (T/128, NH, B), block 256 (4 waves, each 32 q rows), KVBLK=64
// barrier(a): prev tile consumed -> issue V(kv) + K(kv+1) DMA
// barrier(b): after softmax+P-write -> V landed -> PV
// Mask applied via MFMA C-init (precomputed f32 bias). T13 defer-max.
__global__ __launch_bounds__(256) void attn_kernel(
    const unsigned short* __restrict__ q_s, const unsigned short* __restrict__ k_s,
    const unsigned short* __restrict__ vt_s, const float* __restrict__ mzf,
    unsigned short* __restrict__ c) {
  __shared__ __align__(16) unsigned short Klds[2][64 * 64];  // 16KB dbuf
  __shared__ __align__(16) unsigned short Vlds[64 * 64];     // 8KB JIT
  __shared__ __align__(16) unsigned short Plds[4][2048];     // 4KB/wave, 128B rows
  const int b = blockIdx.z, head = blockIdx.y, qb = blockIdx.x;
  const unsigned short* qp = q_s + ((size_t)(b * NH + head) * TSEQ + qb * 128) * HD;
  const unsigned short* kp = k_s + (size_t)(b * NH + head) * TSEQ * HD;
  const unsigned short* vtp = vt_s + (size_t)(b * NH + head) * HD * TSEQ;
  const float* mp = mzf + b * TSEQ;
  const int tid = threadIdx.x, l = tid & 63, w = tid >> 6;
  const int lrow = l & 15, hi = l >> 4;
  char* Vb = reinterpret_cast<char*>(Vlds);
  char* Pb = reinterpret_cast<char*>(&Plds[w][0]);
  const int sr = l >> 3;                       // DMA: lane's row-in-8
  const int sslot = (l & 7) ^ (sr & 7);        // pre-swizzled source slot

  // Q fragments (B-operand): lane holds Q[q = w*32 + qt*16 + lrow][d = ks*32 + hi*8 ..+7]
  short8 qf[2][2];
#pragma unroll
  for (int qt = 0; qt < 2; ++qt)
#pragma unroll
    for (int ks = 0; ks < 2; ++ks)
      qf[qt][ks] = *reinterpret_cast<const short8*>(qp + (size_t)(w * 32 + qt * 16 + lrow) * HD + ks * 32 + hi * 8);

  f32x4 acc[2][4] = {};
  float mreg[2] = {-1e30f, -1e30f};
  float lsum[2] = {0.0f, 0.0f};   // per-lane partial (own 16-k subset); reduced in epilogue

  auto KSTAGE = [&](int kv, int bi) {
#pragma unroll
    for (int p = 0; p < 2; ++p) {
      int rb = w * 16 + p * 8;                 // uniform per wave
      gl2lds16(kp + (size_t)(kv * 64 + rb + sr) * HD + sslot * 8, &Klds[bi][rb * 64]);
    }
  };
  auto VSTAGE = [&](int kv) {
#pragma unroll
    for (int p = 0; p < 2; ++p) {
      int rb = w * 16 + p * 8;                 // d rows
      gl2lds16(vtp + (size_t)(rb + sr) * TSEQ + kv * 64 + sslot * 8, Vlds + rb * 64);
    }
  };

  KSTAGE(0, 0);

  for (int kv = 0; kv < TSEQ / 64; ++kv) {
    const int bi = kv & 1;
    char* Kb = reinterpret_cast<char*>(&Klds[bi][0]);
    __syncthreads();                       // (a) prev tile consumed; K[bi] landed
    VSTAGE(kv);                            // V DMA hides under QK^T + softmax
    if (kv + 1 < TSEQ / 64) KSTAGE(kv + 1, bi ^ 1);

    // mask bias (f32, per k = kt*16 + hi*4 + r) -> MFMA C-init (free add)
    f32x4 mb[4];
#pragma unroll
    for (int kt = 0; kt < 4; ++kt)
      mb[kt] = *reinterpret_cast<const f32x4*>(mp + kv * 64 + kt * 16 + hi * 4);

    // ---- S^T = K Q^T + bias : st[kt][qt], S^T[k = kt*16+hi*4+r][q = qt*16+lrow] ----
    f32x4 st[4][2];
#pragma unroll
    for (int kt = 0; kt < 4; ++kt) { st[kt][0] = mb[kt]; st[kt][1] = mb[kt]; }
#pragma unroll
    for (int ks = 0; ks < 2; ++ks) {
      short8 kf[4];
#pragma unroll
      for (int kt = 0; kt < 4; ++kt) {
        int row = kt * 16 + lrow;
        kf[kt] = *reinterpret_cast<const short8*>(Kb + row * 128 + (((ks * 4 + hi) ^ (row & 7)) << 4));
      }
#pragma unroll
      for (int kt = 0; kt < 4; ++kt)
#pragma unroll
        for (int qt = 0; qt < 2; ++qt)
          st[kt][qt] = __builtin_amdgcn_mfma_f32_16x16x32_bf16(kf[kt], qf[qt][ks], st[kt][qt], 0, 0, 0);
    }

    // ---- online softmax (exp2 domain), T13 defer-max ----
    float mx[2];
#pragma unroll
    for (int qt = 0; qt < 2; ++qt) {
      f32x4 mm;
#pragma unroll
      for (int r = 0; r < 4; ++r)
        mm[r] = fmaxf(fmaxf(st[0][qt][r], st[1][qt][r]), fmaxf(st[2][qt][r], st[3][qt][r]));
      float m = fmaxf(fmaxf(mm[0], mm[1]), fmaxf(mm[2], mm[3]));
      m = fmaxf(m, __shfl_xor(m, 16));
      m = fmaxf(m, __shfl_xor(m, 32));
      mx[qt] = m;
    }
    if (__any(mx[0] > mreg[0] + 8.0f || mx[1] > mreg[1] + 8.0f)) {
      float scl[2];
#pragma unroll
      for (int qt = 0; qt < 2; ++qt) {
        float mnew = fmaxf(mreg[qt], mx[qt]);
        scl[qt] = __builtin_amdgcn_exp2f(mreg[qt] - mnew);
        mreg[qt] = mnew;
        lsum[qt] *= scl[qt];
      }
#pragma unroll
      for (int qt = 0; qt < 2; ++qt)
#pragma unroll
        for (int r = 0; r < 4; ++r) {
          float sc = __shfl(scl[qt], hi * 4 + r);
#pragma unroll
          for (int dc = 0; dc < 4; ++dc) acc[qt][dc][r] *= sc;
        }
    }
#pragma unroll
    for (int qt = 0; qt < 2; ++qt) {
#pragma unroll
      for (int kt = 0; kt < 4; ++kt)
#pragma unroll
        for (int r = 0; r < 4; ++r)
          st[kt][qt][r] = __builtin_amdgcn_exp2f(st[kt][qt][r] - mreg[qt]);
      f32x4 sv = (st[0][qt] + st[1][qt]) + (st[2][qt] + st[3][qt]);
      lsum[qt] += (sv[0] + sv[1]) + (sv[2] + sv[3]);
    }

    // ---- pack P (bf16) -> per-wave LDS, 128B rows, swizzled 16B slots ----
#pragma unroll
    for (int qt = 0; qt < 2; ++qt) {
      int q = qt * 16 + lrow;
#pragma unroll
      for (int kt = 0; kt < 4; ++kt) {
        uint2 pw;
        pw.x = pk2(st[kt][qt][0], st[kt][qt][1]);
        pw.y = pk2(st[kt][qt][2], st[kt][qt][3]);
        *reinterpret_cast<uint2*>(
            Pb + q * 128 + ((((kt * 2 + (hi >> 1)) ^ (q & 7)) & 7) << 4) + ((hi & 1) << 3)) = pw;
      }
    }

    __syncthreads();                       // (b) V landed
    // ---- O += P V ----
#pragma unroll
    for (int ks = 0; ks < 2; ++ks) {
      short8 pa[2], vf[4];
#pragma unroll
      for (int qt = 0; qt < 2; ++qt) {
        int q = qt * 16 + lrow;
        pa[qt] = *reinterpret_cast<const short8*>(Pb + q * 128 + (((ks * 4 + hi) ^ (q & 7)) << 4));
      }
#pragma unroll
      for (int dc = 0; dc < 4; ++dc) {
        int d = dc * 16 + lrow;
        vf[dc] = *reinterpret_cast<const short8*>(Vb + d * 128 + (((ks * 4 + hi) ^ (d & 7)) << 4));
      }
#pragma unroll
      for (int qt = 0; qt < 2; ++qt)
#pragma unroll
        for (int dc = 0; dc < 4; ++dc)
          acc[qt][dc] = __builtin_amdgcn_mfma_f32_16x16x32_bf16(pa[qt], vf[dc], acc[qt][dc], 0, 0, 0);
    }
  }

  // ---- epilogue: reduce lsum across hi groups, O /= lsum, write c (B,T,H) ----
#pragma unroll
  for (int qt = 0; qt < 2; ++qt) {
    lsum[qt] += __shfl_xor(lsum[qt], 16);
    lsum[qt] += __shfl_xor(lsum[qt], 32);
  }
#pragma unroll
  for (int qt = 0; qt < 2; ++qt) {
#pragma unroll
    for (int r = 0; r < 4; ++r) {
      float inv = 1.0f / __shfl(lsum[qt], hi * 4 + r);
      int t = qb * 128 + w * 32 + qt * 16 + hi * 4 + r;
#pragma unroll
      for (int dc = 0; dc < 4; ++dc) {
        int col = head * HD + dc * 16 + lrow;
        c[((size_t)(b * TSEQ) + t) * HDIM + col] = f2bf(acc[qt][dc][r] * inv);
      }
    }
  }
}

extern "C" void kernel_launch(void* const* d_in, const int* in_sizes, int n_in,
                              void* d_out, int out_size, void* d_ws, size_t ws_size,
                              hipStream_t stream) {
  const float* x   = (const float*)d_in[0];
  const int* mask  = (const int*)d_in[1];
  const float* lng = (const float*)d_in[2];
  const float* lnb = (const float*)d_in[3];
  const float* wq  = (const float*)d_in[4];
  const float* bq  = (const float*)d_in[5];
  const float* wk  = (const float*)d_in[6];
  const float* bk  = (const float*)d_in[7];
  const float* wv  = (const float*)d_in[8];
  const float* bv  = (const float*)d_in[9];
  const float* wo  = (const float*)d_in[10];
  const float* bo  = (const float*)d_in[11];
  float* out = (float*)d_out;
  char* ws = (char*)d_ws;

  unsigned short* h   = (unsigned short*)ws;                       // 16MB (B*T*H bf16)
  unsigned short* wbf = (unsigned short*)(ws + (16u << 20));       // 8MB (4 weights bf16)
  unsigned short* qs  = (unsigned short*)(ws + (24u << 20));       // 16MB
  unsigned short* ksb = (unsigned short*)(ws + (40u << 20));       // 16MB
  unsigned short* vt  = (unsigned short*)(ws + (56u << 20));       // 16MB (V^T: B,NH,HD,T)
  float*          mzf = (float*)(ws + (72u << 20));                // 32KB mask bias
  unsigned short* c   = h;  // h dead after QKV GEMM

  convert_w<<<4096, 256, 0, stream>>>(wq, wk, wv, wo, wbf);
  mask_bias<<<BATCH * TSEQ / 256, 256, 0, stream>>>(mask, mzf);
  ln_kernel<<<BATCH * TSEQ, 256, 0, stream>>>(x, lng, lnb, h);
  gemm_k<0><<<dim3(8, 64, 3), 256, 0, stream>>>(h, wbf, bq, bk, bv, qs, ksb, vt, nullptr, nullptr);
  attn_kernel<<<dim3(TSEQ / 128, NH, BATCH), 256, 0, stream>>>(qs, ksb, vt, mzf, c);
  gemm_k<1><<<dim3(8, 64, 1), 256, 0, stream>>>(c, wbf + (size_t)3 * HDIM * HDIM, bo, nullptr, nullptr,
                                                nullptr, nullptr, nullptr, x, out);
}